// Round 1
// baseline (1616.214 us; speedup 1.0000x reference)
//
#include <hip/hip_runtime.h>
#include <hip/hip_bf16.h>

// Problem constants
#define BB   4096
#define SS   10
#define HH   512
#define DIN  1024   // 2H
#define NG   1536   // 3H
#define MROWS 40960 // B*S

typedef __bf16 bf16x8 __attribute__((ext_vector_type(8)));
typedef __bf16 bf16x4 __attribute__((ext_vector_type(4)));
typedef float  f32x4  __attribute__((ext_vector_type(4)));

#define MFMA16(a, b, c) __builtin_amdgcn_mfma_f32_16x16x32_bf16((a), (b), (c), 0, 0, 0)

// Workspace layout (bytes)
constexpr size_t SZ_GX   = (size_t)MROWS * NG * 2;      // 125,829,120
constexpr size_t OFF_GXF = 0;
constexpr size_t OFF_GXB = SZ_GX;
constexpr size_t OFF_XB  = 2 * SZ_GX;                   // X bf16
constexpr size_t SZ_XB   = (size_t)MROWS * DIN * 2;     // 83,886,080
constexpr size_t OFF_WIHF = OFF_XB + SZ_XB;
constexpr size_t SZ_WIH  = (size_t)NG * DIN * 2;        // 3,145,728
constexpr size_t OFF_WIHB = OFF_WIHF + SZ_WIH;
constexpr size_t OFF_WHHF = OFF_WIHB + SZ_WIH;
constexpr size_t SZ_WHH  = (size_t)NG * HH * 2;         // 1,572,864
constexpr size_t OFF_WHHB = OFF_WHHF + SZ_WHH;
constexpr size_t OFF_END  = OFF_WHHB + SZ_WHH;          // ~345 MB

__device__ __forceinline__ void load_lds16(const void* g, void* l) {
    __builtin_amdgcn_global_load_lds(
        (const __attribute__((address_space(1))) void*)g,
        (__attribute__((address_space(3))) void*)l, 16, 0, 0);
}

// ---------------------------------------------------------------------------
// Kernel 1: fp32 -> bf16 cast, 8 elements/thread
// ---------------------------------------------------------------------------
__global__ __launch_bounds__(256) void cast_bf16_8(
    const float* __restrict__ src, __bf16* __restrict__ dst, long n)
{
    long i = ((long)blockIdx.x * 256 + threadIdx.x) * 8;
    if (i >= n) return;
    float4 v0 = *(const float4*)&src[i];
    float4 v1 = *(const float4*)&src[i + 4];
    bf16x8 o = { (__bf16)v0.x, (__bf16)v0.y, (__bf16)v0.z, (__bf16)v0.w,
                 (__bf16)v1.x, (__bf16)v1.y, (__bf16)v1.z, (__bf16)v1.w };
    *(bf16x8*)&dst[i] = o;
}

// ---------------------------------------------------------------------------
// Kernel 2: gx[set] = X @ W_ih[set]^T + b_ih[set]   (bf16 in/out, fp32 acc)
// C = A(M x K) * B(N x K)^T, M=40960, N=1536, K=1024. Tile 128x128, BK=64.
// grid = (N/128=12, M/128=320, 2 sets), block = 256
// ---------------------------------------------------------------------------
__global__ __launch_bounds__(256) void input_gemm(
    const __bf16* __restrict__ Xb,
    const __bf16* __restrict__ Wf, const __bf16* __restrict__ Wb,
    const float* __restrict__ biasf, const float* __restrict__ biasb,
    __bf16* __restrict__ gxf, __bf16* __restrict__ gxb)
{
    __shared__ __bf16 smA[128 * 64];
    __shared__ __bf16 smB[128 * 64];

    const int set = blockIdx.z;
    const __bf16* W   = set ? Wb : Wf;
    const float* bias = set ? biasb : biasf;
    __bf16* gx        = set ? gxb : gxf;

    const int n0 = blockIdx.x * 128;
    const int m0 = blockIdx.y * 128;
    const int tid  = threadIdx.x;
    const int lane = tid & 63;
    const int wid  = tid >> 6;
    const int lm   = lane & 15;
    const int quad = lane >> 4;
    const int m_base = (wid & 1) * 64;
    const int n_base = (wid >> 1) * 64;
    const int srow   = tid >> 3;        // 0..31 staging row within 32-row group
    const int schunk = (tid & 7) * 8;   // staging col (bf16 elems)

    f32x4 acc[4][4] = {};

    for (int kt = 0; kt < 16; ++kt) {
        const int k0 = kt * 64;
        __syncthreads();
#pragma unroll
        for (int ra = 0; ra < 4; ++ra) {
            int row = ra * 32 + srow;
            load_lds16(&Xb[(size_t)(m0 + row) * DIN + k0 + schunk],
                       &smA[row * 64 + schunk]);
        }
#pragma unroll
        for (int ra = 0; ra < 4; ++ra) {
            int row = ra * 32 + srow;
            load_lds16(&W[(size_t)(n0 + row) * DIN + k0 + schunk],
                       &smB[row * 64 + schunk]);
        }
        __syncthreads();
#pragma unroll
        for (int kk = 0; kk < 2; ++kk) {
            const int kof = kk * 32 + quad * 8;
            bf16x8 a[4], b[4];
#pragma unroll
            for (int mt = 0; mt < 4; ++mt)
                a[mt] = *(const bf16x8*)&smA[(m_base + mt * 16 + lm) * 64 + kof];
#pragma unroll
            for (int nt = 0; nt < 4; ++nt)
                b[nt] = *(const bf16x8*)&smB[(n_base + nt * 16 + lm) * 64 + kof];
#pragma unroll
            for (int mt = 0; mt < 4; ++mt)
#pragma unroll
                for (int nt = 0; nt < 4; ++nt)
                    acc[mt][nt] = MFMA16(a[mt], b[nt], acc[mt][nt]);
        }
    }

    // Epilogue: + bias, cast bf16, store. D layout: row=quad*4+r, col=lm.
#pragma unroll
    for (int mt = 0; mt < 4; ++mt) {
#pragma unroll
        for (int nt = 0; nt < 4; ++nt) {
            const int col = n0 + n_base + nt * 16 + lm;
            const float bv = bias[col];
#pragma unroll
            for (int r = 0; r < 4; ++r) {
                const int row = m0 + m_base + mt * 16 + quad * 4 + r;
                gx[(size_t)row * NG + col] = (__bf16)(acc[mt][nt][r] + bv);
            }
        }
    }
}

// ---------------------------------------------------------------------------
// Kernel 3: persistent recurrence. grid=256 (64 batch-tiles x 4 streams),
// block=512 (8 waves). Each WG owns 64 batch rows of one stream for all 10
// steps. h state: single 64x512 bf16 LDS buffer, rebuilt each step from the
// fp32 h_new written to `out` at the previous step (mask reset to hx).
// stream: 0=fwd/f, 1=fwd/b, 2=bwd/f, 3=bwd/b; out col offset = stream*512.
// ---------------------------------------------------------------------------
__global__ __launch_bounds__(512) void gru_rec(
    const __bf16* __restrict__ whhf, const __bf16* __restrict__ whhb,
    const float* __restrict__ bhhf, const float* __restrict__ bhhb,
    const __bf16* __restrict__ gxf, const __bf16* __restrict__ gxb,
    const int* __restrict__ mfr, const int* __restrict__ mbk,
    const float* __restrict__ hx, float* out)
{
    __shared__ __bf16 hbuf[64 * 512];

    const int bx = blockIdx.x;
    const int stream = bx & 3;
    const int b0 = (bx >> 2) * 64;
    const int set = stream & 1;
    const int dir = stream >> 1;

    const __bf16* whh = set ? whhb : whhf;
    const float* bhh  = set ? bhhb : bhhf;
    const __bf16* gx  = set ? gxb : gxf;
    const int* mask   = dir ? mbk : mfr;
    const float* hx0  = hx + set * HH;
    const int ocol0   = stream * HH;

    const int tid  = threadIdx.x;
    const int lane = tid & 63;
    const int wid  = tid >> 6;   // 0..7
    const int lm   = lane & 15;
    const int quad = lane >> 4;
    const int wcol0 = wid * 64;

    // build-phase assignment: one row per 8 threads
    const int brow = tid >> 3;          // 0..63
    const int bc0  = (tid & 7) * 64;    // 64-col chunk

    for (int i = 0; i < 10; ++i) {
        const int t = dir ? (9 - i) : i;

        // ---- build h_u (masked) into LDS as bf16 ----
        {
            const int m = mask[(size_t)(b0 + brow) * SS + i];
            const bool reset = (i == 0) || (m != 1);
            const float* src;
            if (reset) {
                src = &hx0[bc0];
            } else {
                const int tp = dir ? (10 - i) : (i - 1);
                src = &out[((size_t)(b0 + brow) * SS + tp) * (4 * HH) + ocol0 + bc0];
            }
#pragma unroll
            for (int c = 0; c < 64; c += 4) {
                float4 v = *(const float4*)&src[c];
                bf16x4 b4 = { (__bf16)v.x, (__bf16)v.y, (__bf16)v.z, (__bf16)v.w };
                *(bf16x4*)&hbuf[brow * 512 + bc0 + c] = b4;
            }
        }
        __syncthreads();

        // ---- gh = h_u @ whh^T (per-wave 64-col slice), fused elementwise ----
        for (int jt = 0; jt < 4; ++jt) {
            const int jc = wcol0 + jt * 16;
            const __bf16* wr = whh + (size_t)(jc + lm) * HH;
            f32x4 acc[4][3] = {};
#pragma unroll 4
            for (int kk = 0; kk < 16; ++kk) {
                const int k = kk * 32 + quad * 8;
                bf16x8 a0 = *(const bf16x8*)&hbuf[(lm)      * 512 + k];
                bf16x8 a1 = *(const bf16x8*)&hbuf[(16 + lm) * 512 + k];
                bf16x8 a2 = *(const bf16x8*)&hbuf[(32 + lm) * 512 + k];
                bf16x8 a3 = *(const bf16x8*)&hbuf[(48 + lm) * 512 + k];
                bf16x8 br = *(const bf16x8*)&wr[k];
                bf16x8 bz = *(const bf16x8*)&wr[(size_t)512 * HH + k];
                bf16x8 bn = *(const bf16x8*)&wr[(size_t)1024 * HH + k];
                acc[0][0] = MFMA16(a0, br, acc[0][0]);
                acc[1][0] = MFMA16(a1, br, acc[1][0]);
                acc[2][0] = MFMA16(a2, br, acc[2][0]);
                acc[3][0] = MFMA16(a3, br, acc[3][0]);
                acc[0][1] = MFMA16(a0, bz, acc[0][1]);
                acc[1][1] = MFMA16(a1, bz, acc[1][1]);
                acc[2][1] = MFMA16(a2, bz, acc[2][1]);
                acc[3][1] = MFMA16(a3, bz, acc[3][1]);
                acc[0][2] = MFMA16(a0, bn, acc[0][2]);
                acc[1][2] = MFMA16(a1, bn, acc[1][2]);
                acc[2][2] = MFMA16(a2, bn, acc[2][2]);
                acc[3][2] = MFMA16(a3, bn, acc[3][2]);
            }

            const int col = jc + lm;
            const float bhr = bhh[col];
            const float bhz = bhh[HH + col];
            const float bhn = bhh[2 * HH + col];
#pragma unroll
            for (int mt = 0; mt < 4; ++mt) {
#pragma unroll
                for (int r = 0; r < 4; ++r) {
                    const int row = mt * 16 + quad * 4 + r;
                    const int b = b0 + row;
                    const size_t gi = ((size_t)b * SS + t) * NG + col;
                    const float gxr = (float)gx[gi];
                    const float gxz = (float)gx[gi + HH];
                    const float gxn = (float)gx[gi + 2 * HH];
                    const float ghr = acc[mt][0][r] + bhr;
                    const float ghz = acc[mt][1][r] + bhz;
                    const float ghn = acc[mt][2][r] + bhn;
                    const float rg = 1.0f / (1.0f + __expf(-(gxr + ghr)));
                    const float zg = 1.0f / (1.0f + __expf(-(gxz + ghz)));
                    const float ng = tanhf(gxn + rg * ghn);
                    const float hu = (float)hbuf[row * 512 + col];
                    const float hn = (1.0f - zg) * ng + zg * hu;
                    out[((size_t)b * SS + t) * (4 * HH) + ocol0 + col] = hn;
                }
            }
        }
        __syncthreads();  // all h_new stores + hbuf reads done before next build
    }
}

// ---------------------------------------------------------------------------
extern "C" void kernel_launch(void* const* d_in, const int* in_sizes, int n_in,
                              void* d_out, int out_size, void* d_ws, size_t ws_size,
                              hipStream_t stream)
{
    (void)in_sizes; (void)n_in; (void)out_size;
    if (ws_size < OFF_END) return;  // workspace too small — fail loudly via absmax

    const float* X    = (const float*)d_in[0];
    const int*   mfr  = (const int*)d_in[1];
    const int*   mbk  = (const int*)d_in[2];
    const float* hx   = (const float*)d_in[3];
    const float* wihf = (const float*)d_in[4];
    const float* whhf = (const float*)d_in[5];
    const float* bihf = (const float*)d_in[6];
    const float* bhhf = (const float*)d_in[7];
    const float* wihb = (const float*)d_in[8];
    const float* whhb = (const float*)d_in[9];
    const float* bihb = (const float*)d_in[10];
    const float* bhhb = (const float*)d_in[11];
    float* out = (float*)d_out;
    char*  ws  = (char*)d_ws;

    __bf16* gxf = (__bf16*)(ws + OFF_GXF);
    __bf16* gxb = (__bf16*)(ws + OFF_GXB);
    __bf16* Xb  = (__bf16*)(ws + OFF_XB);
    __bf16* Wif = (__bf16*)(ws + OFF_WIHF);
    __bf16* Wib = (__bf16*)(ws + OFF_WIHB);
    __bf16* Whf = (__bf16*)(ws + OFF_WHHF);
    __bf16* Whb = (__bf16*)(ws + OFF_WHHB);

    // casts to bf16
    cast_bf16_8<<<20480, 256, 0, stream>>>(X,    Xb,  (long)MROWS * DIN);
    cast_bf16_8<<<768,   256, 0, stream>>>(wihf, Wif, (long)NG * DIN);
    cast_bf16_8<<<768,   256, 0, stream>>>(wihb, Wib, (long)NG * DIN);
    cast_bf16_8<<<384,   256, 0, stream>>>(whhf, Whf, (long)NG * HH);
    cast_bf16_8<<<384,   256, 0, stream>>>(whhb, Whb, (long)NG * HH);

    // input GEMMs (both weight sets)
    input_gemm<<<dim3(12, 320, 2), 256, 0, stream>>>(Xb, Wif, Wib, bihf, bihb, gxf, gxb);

    // persistent recurrence (4 streams x 64 batch tiles)
    gru_rec<<<256, 512, 0, stream>>>(Whf, Whb, bhhf, bhhb, gxf, gxb, mfr, mbk, hx, out);
}